// Round 14
// baseline (288.139 us; speedup 1.0000x reference)
//
#include <hip/hip_runtime.h>
#include <hip/hip_bf16.h>

#define TDIM 2048
#define BDIM 4
#define CDIM 1024
#define HDIM 16
#define DH   64

typedef __hip_bfloat16 bf16;
typedef __attribute__((ext_vector_type(8))) short bf16x8;
typedef __attribute__((ext_vector_type(4))) short bf16x4;
typedef __attribute__((ext_vector_type(4))) float f32x4;

// async global->LDS, 16B per lane; LDS dest = wave-uniform base + lane*16
__device__ __forceinline__ void async_ld16(const bf16* g, bf16* l) {
    __builtin_amdgcn_global_load_lds(
        (const __attribute__((address_space(1))) unsigned int*)g,
        (__attribute__((address_space(3))) unsigned int*)l, 16, 0, 0);
}

__device__ __forceinline__ unsigned short bf16bits(float x) {
    bf16 b = __float2bfloat16(x);
    return *(unsigned short*)&b;
}

// v_exp_f32 is natively 2^x; exp2f avoids __expf's extra 1/ln2 multiply
__device__ __forceinline__ float fast_exp2(float x) {
#if __has_builtin(__builtin_amdgcn_exp2f)
    return __builtin_amdgcn_exp2f(x);
#else
    return exp2f(x);
#endif
}

// 16x16x16 bf16 MFMA (k=16): verified working (passed correctness)
__device__ __forceinline__ f32x4 mfma_16x16x16_bf16(bf16x4 a, bf16x4 b, f32x4 c) {
#if __has_builtin(__builtin_amdgcn_mfma_f32_16x16x16_bf16)
    return __builtin_amdgcn_mfma_f32_16x16x16_bf16(a, b, c, 0, 0, 0);
#elif __has_builtin(__builtin_amdgcn_mfma_f32_16x16x16bf16_1k)
    return __builtin_amdgcn_mfma_f32_16x16x16bf16_1k(a, b, c, 0, 0, 0);
#else
    asm volatile("v_mfma_f32_16x16x16_bf16 %0, %1, %2, %0"
                 : "+v"(c) : "v"(a), "v"(b));
    return c;
#endif
}

// ---------------------------------------------------------------------------
__global__ void convert_x4(const float4* __restrict__ src, ushort4* __restrict__ dst, int n4) {
    int i = blockIdx.x * blockDim.x + threadIdx.x;
    if (i >= n4) return;
    float4 v = src[i];
    ushort4 o;
    o.x = bf16bits(v.x); o.y = bf16bits(v.y);
    o.z = bf16bits(v.z); o.w = bf16bits(v.w);
    dst[i] = o;
}

__global__ void convert_biases(const float* __restrict__ b0, const float* __restrict__ b1,
                               const float* __restrict__ b2, const float* __restrict__ b3,
                               bf16* __restrict__ dst) {
    int i = blockIdx.x * blockDim.x + threadIdx.x;   // 0..4095
    int which = i >> 10, j = i & 1023;
    const float* src = (which == 0) ? b0 : (which == 1) ? b1 : (which == 2) ? b2 : b3;
    dst[i] = __float2bfloat16(src[j]);
}

// ---------------------------------------------------------------------------
// LDS-tiled transpose, fused over Wq/Wk/Wv: z = which*16 + h.
// ---------------------------------------------------------------------------
__global__ __launch_bounds__(256) void transpose_qkv_kernel(
    const float* __restrict__ Wq, const float* __restrict__ Wk, const float* __restrict__ Wv,
    bf16* __restrict__ WqT, bf16* __restrict__ WkT, bf16* __restrict__ WvT) {
    __shared__ float tile[64][65];
    const int which = blockIdx.z >> 4, h = blockIdx.z & 15;
    const float* W  = ((which == 0) ? Wq  : (which == 1) ? Wk  : Wv)  + (size_t)h * CDIM * DH;
    bf16*        WT = ((which == 0) ? WqT : (which == 1) ? WkT : WvT) + (size_t)h * CDIM * DH;
    const int c0 = blockIdx.x * 64;
    for (int it = 0; it < 16; it++) {
        int e = it * 256 + threadIdx.x;
        int r = e >> 6, col = e & 63;
        tile[r][col] = W[(size_t)(c0 + r) * DH + col];
    }
    __syncthreads();
    for (int it = 0; it < 16; it++) {
        int e = it * 256 + threadIdx.x;
        int r = e >> 6, col = e & 63;
        WT[(size_t)r * CDIM + c0 + col] = __float2bfloat16(tile[col][r]);
    }
}

__global__ __launch_bounds__(256) void transpose_wo_kernel(
    const float* __restrict__ W, bf16* __restrict__ WT) {
    __shared__ float tile[64][65];
    const int c0 = blockIdx.x * 64, d0 = blockIdx.y * 64;
    for (int it = 0; it < 16; it++) {
        int e = it * 256 + threadIdx.x;
        int r = e >> 6, col = e & 63;
        tile[r][col] = W[(size_t)(c0 + r) * CDIM + d0 + col];
    }
    __syncthreads();
    for (int it = 0; it < 16; it++) {
        int e = it * 256 + threadIdx.x;
        int r = e >> 6, col = e & 63;
        WT[(size_t)(d0 + r) * CDIM + c0 + col] = __float2bfloat16(tile[col][r]);
    }
}

// ---------------------------------------------------------------------------
// 128x128 MFMA GEMM, QKV variant, with:
//  - T1 XCD swizzle (r13, measured win): XCD = M-octant.
//  - DBUF single-barrier K-loop (r8-proven attn pattern): stage kt+1 into
//    buf^1 BEFORE computing kt, one barrier per K-step (32 barriers, was 64);
//    the compiler's vmcnt(0) drain lands after the 16-MFMA compute phase.
//  - z==2 (V) epilogue writes Vt[bh][d][t] DIRECTLY (r indexes 4 consecutive
//    t -> one ushort4 per fragment, bit-identical values) -- the separate
//    transpose_v kernel (32MB round-trip) is eliminated.
// Q pre-scaled by (1/32)*log2(e) so attention can use native exp2.
// ---------------------------------------------------------------------------
__global__ __launch_bounds__(256) void proj_qkv_kernel(
    const bf16* __restrict__ X,
    const bf16* __restrict__ WqT, const bf16* __restrict__ WkT, const bf16* __restrict__ WvT,
    const bf16* __restrict__ bq,  const bf16* __restrict__ bk,  const bf16* __restrict__ bvv,
    bf16* __restrict__ Qo, bf16* __restrict__ Ko, bf16* __restrict__ Vt)
{
    // XCD-aware decode (lin%8 = XCD by HW round-robin)
    const int lin  = blockIdx.x + (int)gridDim.x * (blockIdx.y + (int)gridDim.y * blockIdx.z);
    const int xcd  = lin & 7;
    const int s    = lin >> 3;          // 0..191
    const int mloc = s & 7;             // M-tile within octant
    const int rest = s >> 3;            // 0..23
    const int nblk = rest & 7;          // N-tile
    const int z    = rest >> 3;         // 0..2

    const bf16* Bt   = (z == 0) ? WqT : (z == 1) ? WkT : WvT;
    const bf16* bias = (z == 0) ? bq  : (z == 1) ? bk  : bvv;

    __shared__ __align__(16) bf16 As[2 * 128 * 32];   // 2 bufs x 8KB
    __shared__ __align__(16) bf16 Bs[2 * 128 * 32];

    const int tid  = threadIdx.x;
    const int lane = tid & 63;
    const int wave = tid >> 6;
    const int wr = wave >> 1, wc = wave & 1;
    const int l15 = lane & 15, quad = lane >> 4;

    const int blockM = (xcd * 8 + mloc) * 128;
    const int blockN = nblk * 128;

    f32x4 acc[4][4];
    for (int i = 0; i < 4; i++)
        for (int j = 0; j < 4; j++)
            acc[i][j] = (f32x4){0.f, 0.f, 0.f, 0.f};

    const int srow = lane >> 2, scol = (lane & 3) * 8;
#define PSTAGE(k0, buf)                                                          \
    do {                                                                         \
        for (int cc = 0; cc < 2; cc++) {                                         \
            int chunk = wave * 2 + cc;                                           \
            int row = chunk * 16 + srow;                                         \
            async_ld16(&X [(size_t)(blockM + row) * CDIM + (k0) + scol],         \
                       &As[(buf) * 4096 + chunk * 512]);                         \
            async_ld16(&Bt[(size_t)(blockN + row) * CDIM + (k0) + scol],         \
                       &Bs[(buf) * 4096 + chunk * 512]);                         \
        }                                                                        \
    } while (0)

    PSTAGE(0, 0);
    __syncthreads();

    int cur = 0;
    for (int kt = 0; kt < 32; kt++) {
        if (kt + 1 < 32) PSTAGE((kt + 1) * 32, cur ^ 1);

        const bf16* Ap = As + cur * 4096;
        const bf16* Bp = Bs + cur * 4096;
        bf16x8 af[4], bfr[4];
        for (int mi = 0; mi < 4; mi++)
            af[mi] = *(const bf16x8*)&Ap[(wr * 64 + mi * 16 + l15) * 32 + quad * 8];
        for (int ni = 0; ni < 4; ni++)
            bfr[ni] = *(const bf16x8*)&Bp[(wc * 64 + ni * 16 + l15) * 32 + quad * 8];

        for (int mi = 0; mi < 4; mi++)
            for (int ni = 0; ni < 4; ni++)
                acc[mi][ni] = __builtin_amdgcn_mfma_f32_16x16x32_bf16(
                    af[mi], bfr[ni], acc[mi][ni], 0, 0, 0);
        __syncthreads();   // drains kt+1 staging + protects buffer swap
        cur ^= 1;
    }
#undef PSTAGE

    for (int mi = 0; mi < 4; mi++) {
        int mbase = blockM + wr * 64 + mi * 16 + quad * 4;
        int b = mbase >> 11, t = mbase & 2047;
        for (int ni = 0; ni < 4; ni++) {
            int n = blockN + wc * 64 + ni * 16 + l15;
            float bval = __bfloat162float(bias[n]);
            int h = n >> 6, d = n & 63;
            if (z == 2) {
                // V: write transposed layout directly, 4 consecutive t
                unsigned short pk[4];
                for (int r = 0; r < 4; r++) pk[r] = bf16bits(acc[mi][ni][r] + bval);
                *(ushort4*)&Vt[(((size_t)b * HDIM + h) * DH + d) * TDIM + t] = *(ushort4*)pk;
            } else {
                for (int r = 0; r < 4; r++) {
                    float val = acc[mi][ni][r] + bval;
                    size_t idx = (((size_t)b * HDIM + h) * TDIM + (t + r)) * DH + d;
                    if (z == 0) Qo[idx] = __float2bfloat16(val * 0.045084439f); // (1/32)*log2(e)
                    else        Ko[idx] = __float2bfloat16(val);
                }
            }
        }
    }
}

// ---------------------------------------------------------------------------
// Output projection: Y[M,K] @ WoT[N,K]^T + bo -> fp32 Out
// T1 XCD swizzle + dbuf single-barrier K-loop (same rationale as proj_qkv).
// ---------------------------------------------------------------------------
__global__ __launch_bounds__(256) void proj_out_kernel(
    const bf16* __restrict__ X, const bf16* __restrict__ Bt,
    const bf16* __restrict__ bias, float* __restrict__ Out)
{
    const int lin  = blockIdx.x + (int)gridDim.x * blockIdx.y;   // 0..511
    const int xcd  = lin & 7;
    const int s    = lin >> 3;      // 0..63
    const int mloc = s & 7;
    const int nblk = s >> 3;        // 0..7

    __shared__ __align__(16) bf16 As[2 * 128 * 32];
    __shared__ __align__(16) bf16 Bs[2 * 128 * 32];

    const int tid  = threadIdx.x;
    const int lane = tid & 63;
    const int wave = tid >> 6;
    const int wr = wave >> 1, wc = wave & 1;
    const int l15 = lane & 15, quad = lane >> 4;

    const int blockM = (xcd * 8 + mloc) * 128;
    const int blockN = nblk * 128;

    f32x4 acc[4][4];
    for (int i = 0; i < 4; i++)
        for (int j = 0; j < 4; j++)
            acc[i][j] = (f32x4){0.f, 0.f, 0.f, 0.f};

    const int srow = lane >> 2, scol = (lane & 3) * 8;
#define PSTAGE(k0, buf)                                                          \
    do {                                                                         \
        for (int cc = 0; cc < 2; cc++) {                                         \
            int chunk = wave * 2 + cc;                                           \
            int row = chunk * 16 + srow;                                         \
            async_ld16(&X [(size_t)(blockM + row) * CDIM + (k0) + scol],         \
                       &As[(buf) * 4096 + chunk * 512]);                         \
            async_ld16(&Bt[(size_t)(blockN + row) * CDIM + (k0) + scol],         \
                       &Bs[(buf) * 4096 + chunk * 512]);                         \
        }                                                                        \
    } while (0)

    PSTAGE(0, 0);
    __syncthreads();

    int cur = 0;
    for (int kt = 0; kt < 32; kt++) {
        if (kt + 1 < 32) PSTAGE((kt + 1) * 32, cur ^ 1);

        const bf16* Ap = As + cur * 4096;
        const bf16* Bp = Bs + cur * 4096;
        bf16x8 af[4], bfr[4];
        for (int mi = 0; mi < 4; mi++)
            af[mi] = *(const bf16x8*)&Ap[(wr * 64 + mi * 16 + l15) * 32 + quad * 8];
        for (int ni = 0; ni < 4; ni++)
            bfr[ni] = *(const bf16x8*)&Bp[(wc * 64 + ni * 16 + l15) * 32 + quad * 8];

        for (int mi = 0; mi < 4; mi++)
            for (int ni = 0; ni < 4; ni++)
                acc[mi][ni] = __builtin_amdgcn_mfma_f32_16x16x32_bf16(
                    af[mi], bfr[ni], acc[mi][ni], 0, 0, 0);
        __syncthreads();
        cur ^= 1;
    }
#undef PSTAGE

    for (int mi = 0; mi < 4; mi++) {
        int mbase = blockM + wr * 64 + mi * 16 + quad * 4;
        for (int ni = 0; ni < 4; ni++) {
            int n = blockN + wc * 64 + ni * 16 + l15;
            float bval = __bfloat162float(bias[n]);
            for (int r = 0; r < 4; r++)
                Out[(size_t)(mbase + r) * CDIM + n] = acc[mi][ni][r] + bval;
        }
    }
}

// ---------------------------------------------------------------------------
// Flash attention, causal.  r12/r13 version unchanged (81-82us measured):
// 128-q tiles, 4 waves, 2 q-groups/wave, gload_lds swizzle staging,
// 2-buffer single-barrier loop, T1 XCD swizzle (FETCH 112->24.6MB).
// ---------------------------------------------------------------------------
__global__ __launch_bounds__(256, 4) void attn_kernel(
    const bf16* __restrict__ Q, const bf16* __restrict__ Kb,
    const bf16* __restrict__ Vt, bf16* __restrict__ Y)
{
    // XCD-aware decode: lin -> (bh, qT) such that lin%8 is constant per bh
    const int lin  = blockIdx.x + (int)gridDim.x * blockIdx.y;   // 0..1023
    const int slot = lin >> 3;                                   // 0..127
    const int bh   = (lin & 7) * 8 + (slot >> 4);                // 0..63
    const int qT   = 15 - (slot & 15);                           // heavy first
    const int qBase = qT * 128;
    const int tid  = threadIdx.x;
    const int lane = tid & 63, wave = tid >> 6;          // wave 0..3
    const int l15 = lane & 15, quad = lane >> 4;

    __shared__ __align__(16) bf16 smem[2 * 2 * 64 * 64];     // 32 KiB, 2 bufs
    // buf b: K at smem + b*8192, V at smem + b*8192 + 4096 (stride-64 rows)

    // Q B-fragments: group g rows = qBase + g*64 + wave*16 + l15
    bf16x8 qf[2][2];
    for (int g = 0; g < 2; g++) {
        const size_t qrow = (size_t)bh * TDIM + qBase + g * 64 + wave * 16 + l15;
        qf[g][0] = *(const bf16x8*)&Q[qrow * DH + quad * 8];
        qf[g][1] = *(const bf16x8*)&Q[qrow * DH + 32 + quad * 8];
    }

    // O^T accumulators: o[g][mt][r] -> d = mt*16+quad*4+r, q = l15
    f32x4 o[2][4];
    for (int g = 0; g < 2; g++)
        for (int mt = 0; mt < 4; mt++)
            o[g][mt] = (f32x4){0.f, 0.f, 0.f, 0.f};
    float lsum[2] = {0.f, 0.f};

    // --- staging geometry: wave w covers rows w*16 .. w*16+15 --------------
    // lane l: row = base + (l>>3); base%8==0 so row&7 == l>>3.
    // inverse-swizzled source col8 = (l&7) ^ (l>>3)  (per-lane constant)
    const int srow = (wave << 4) + (lane >> 3);
    const int ssc  = (((lane & 7) ^ (lane >> 3)) << 3);         // elem offset
    const bf16* kSrc0 = Kb + ((size_t)bh * TDIM + srow) * DH + ssc;   // +kt*64*DH, +8*DH
    const bf16* vSrc0 = Vt + ((size_t)bh * DH + srow) * TDIM + ssc;   // +kt*64,    +8*TDIM

    // read-side swizzle constants
    const int swA   = l15 & 7;                         // row&7 for fragment rows
    const int kcol0 = ((quad ^ swA) << 3);             // logical col8=quad
    const int kcol1 = (((4 + quad) ^ swA) << 3);       // logical col8=4+quad
    const int u2    = quad >> 1, intra = ((quad & 1) << 2);

    const int nkt  = 2 * qT + 2;
    const int qloc = wave * 16 + l15;    // q offset within a group's 64 rows

    // wave-private staging bases (buffer-relative)
    bf16* kD0 = smem + (wave * 16) * 64;
    bf16* vD0 = smem + 4096 + (wave * 16) * 64;

#define STAGE(tile, buf)                                            \
    do {                                                            \
        const bf16* kS_ = kSrc0 + (size_t)(tile) * 64 * DH;         \
        const bf16* vS_ = vSrc0 + (size_t)(tile) * 64;              \
        bf16* kD_ = kD0 + (buf) * 8192;                             \
        bf16* vD_ = vD0 + (buf) * 8192;                             \
        async_ld16(kS_,            kD_);                            \
        async_ld16(kS_ + 8 * DH,   kD_ + 8 * 64);                   \
        async_ld16(vS_,            vD_);                            \
        async_ld16(vS_ + 8 * TDIM, vD_ + 8 * 64);                   \
    } while (0)

    STAGE(0, 0);
    __syncthreads();   // tile 0 resident

    int cur = 0;
    for (int kt = 0; kt < nkt; kt++) {
        if (kt + 1 < nkt) STAGE(kt + 1, cur ^ 1);   // issued early, drained by
                                                    // the trailing barrier
        const bf16* Ks = smem + cur * 8192;
        const bf16* Vs = Ks + 4096;

        const int dg = kt - 2 * qT;   // <0: both full; 0: g0 diag; 1: g1 diag, g0 done
        for (int nt = 0; nt < 4; nt++) {
            // K A-frags for this 16-key chunk (swizzled cols, shared by groups)
            bf16x8 kf0 = *(const bf16x8*)&Ks[(nt * 16 + l15) * 64 + kcol0];
            bf16x8 kf1 = *(const bf16x8*)&Ks[(nt * 16 + l15) * 64 + kcol1];
            // V A-frags (16x16x16): logical elem col nt*16+quad*4
            bf16x4 vA[4];
            for (int mt = 0; mt < 4; mt++)
                vA[mt] = *(const bf16x4*)&Vs[(mt * 16 + l15) * 64 +
                                             (((nt * 2 + u2) ^ swA) << 3) + intra];

            for (int g = 0; g < 2; g++) {
                if (dg == 1 && g == 0) continue;      // group 0 causal range done
                f32x4 s = (f32x4){0.f, 0.f, 0.f, 0.f};
                s = __builtin_amdgcn_mfma_f32_16x16x32_bf16(kf0, qf[g][0], s, 0, 0, 0);
                s = __builtin_amdgcn_mfma_f32_16x16x32_bf16(kf1, qf[g][1], s, 0, 0, 0);

                const bool diag = (dg == g);
                bf16x4 pb;
                for (int r = 0; r < 4; r++) {
                    float pe = fast_exp2(s[r]);
                    if (diag && (nt * 16 + quad * 4 + r > qloc)) pe = 0.f;
                    lsum[g] += pe;
                    pb[r] = (short)bf16bits(pe);
                }
                for (int mt = 0; mt < 4; mt++)
                    o[g][mt] = mfma_16x16x16_bf16(vA[mt], pb, o[g][mt]);
            }
        }
        __syncthreads();   // drains kt+1 loads + protects buffer swap
        cur ^= 1;
    }
#undef STAGE

    // ---- epilogue: per group, normalize, LDS transpose, coalesced store ----
    const int b = bh >> 4, h = bh & 15;
    unsigned short* sm = (unsigned short*)smem;
    for (int g = 0; g < 2; g++) {
        float v = lsum[g];
        v += __shfl_xor(v, 16, 64);
        v += __shfl_xor(v, 32, 64);
        const float inv = 1.0f / v;

        // o -> LDS wave-private slice [q row][d col], stride 72
        for (int mt = 0; mt < 4; mt++) {
            unsigned short pk[4];
            for (int r = 0; r < 4; r++) pk[r] = bf16bits(o[g][mt][r] * inv);
            *(ushort4*)&sm[(wave * 16 + l15) * 72 + mt * 16 + quad * 4] = *(ushort4*)pk;
        }
        // same-wave readback, coalesced global store
        const int qq = lane >> 2, part = lane & 3;
        const int t = qBase + g * 64 + wave * 16 + qq;
        uint4 c0 = *(const uint4*)&sm[(wave * 16 + qq) * 72 + part * 16];
        uint4 c1 = *(const uint4*)&sm[(wave * 16 + qq) * 72 + part * 16 + 8];
        *(uint4*)&Y[((size_t)b * TDIM + t) * CDIM + h * DH + part * 16]     = c0;
        *(uint4*)&Y[((size_t)b * TDIM + t) * CDIM + h * DH + part * 16 + 8] = c1;
    }
}

// ---------------------------------------------------------------------------
extern "C" void kernel_launch(void* const* d_in, const int* in_sizes, int n_in,
                              void* d_out, int out_size, void* d_ws, size_t ws_size,
                              hipStream_t stream) {
    (void)in_sizes; (void)n_in; (void)out_size; (void)ws_size;

    char* ws = (char*)d_ws;
    const size_t SZ_BHTD = (size_t)BDIM * HDIM * TDIM * DH * sizeof(bf16);  // 16 MiB
    const size_t SZ_W    = (size_t)HDIM * CDIM * DH * sizeof(bf16);         // 2 MiB
    bf16* Qb  = (bf16*)(ws);
    bf16* Kb  = (bf16*)(ws + SZ_BHTD);
    bf16* Vt  = (bf16*)(ws + 2 * SZ_BHTD);
    bf16* Y   = (bf16*)(ws + 3 * SZ_BHTD);
    bf16* WqT = (bf16*)(ws + 4 * SZ_BHTD);
    bf16* WkT = (bf16*)(ws + 4 * SZ_BHTD + SZ_W);
    bf16* WvT = (bf16*)(ws + 4 * SZ_BHTD + 2 * SZ_W);
    bf16* WoT = (bf16*)(ws + 4 * SZ_BHTD + 3 * SZ_W);
    bf16* xC  = (bf16*)(ws + 4 * SZ_BHTD + 4 * SZ_W);                       // 16 MiB
    bf16* bqC = (bf16*)(ws + 5 * SZ_BHTD + 4 * SZ_W);
    bf16* bkC = bqC + 1024;
    bf16* bvC = bqC + 2048;
    bf16* boC = bqC + 3072;

    const int nX4 = (BDIM * TDIM * CDIM) / 4;
    convert_x4<<<nX4 / 256, 256, 0, stream>>>((const float4*)d_in[0], (ushort4*)xC, nX4);
    convert_biases<<<16, 256, 0, stream>>>((const float*)d_in[2], (const float*)d_in[4],
                                           (const float*)d_in[6], (const float*)d_in[8], bqC);

    transpose_qkv_kernel<<<dim3(CDIM / 64, 1, 48), 256, 0, stream>>>(
        (const float*)d_in[1], (const float*)d_in[3], (const float*)d_in[5], WqT, WkT, WvT);
    transpose_wo_kernel<<<dim3(CDIM / 64, CDIM / 64), 256, 0, stream>>>(
        (const float*)d_in[7], WoT);

    dim3 gq(CDIM / 128, (BDIM * TDIM) / 128, 3);
    proj_qkv_kernel<<<gq, 256, 0, stream>>>(xC, WqT, WkT, WvT, bqC, bkC, bvC, Qb, Kb, Vt);

    attn_kernel<<<dim3(TDIM / 128, BDIM * HDIM), 256, 0, stream>>>(Qb, Kb, Vt, Y);

    proj_out_kernel<<<dim3(CDIM / 128, (BDIM * TDIM) / 128), 256, 0, stream>>>(
        Y, WoT, boC, (float*)d_out);
}

// Round 15
// 268.957 us; speedup vs baseline: 1.0713x; 1.0713x over previous
//
#include <hip/hip_runtime.h>
#include <hip/hip_bf16.h>

#define TDIM 2048
#define BDIM 4
#define CDIM 1024
#define HDIM 16
#define DH   64

typedef __hip_bfloat16 bf16;
typedef __attribute__((ext_vector_type(8))) short bf16x8;
typedef __attribute__((ext_vector_type(4))) short bf16x4;
typedef __attribute__((ext_vector_type(4))) float f32x4;

// async global->LDS, 16B per lane; LDS dest = wave-uniform base + lane*16
__device__ __forceinline__ void async_ld16(const bf16* g, bf16* l) {
    __builtin_amdgcn_global_load_lds(
        (const __attribute__((address_space(1))) unsigned int*)g,
        (__attribute__((address_space(3))) unsigned int*)l, 16, 0, 0);
}

__device__ __forceinline__ unsigned short bf16bits(float x) {
    bf16 b = __float2bfloat16(x);
    return *(unsigned short*)&b;
}

// v_exp_f32 is natively 2^x; exp2f avoids __expf's extra 1/ln2 multiply
__device__ __forceinline__ float fast_exp2(float x) {
#if __has_builtin(__builtin_amdgcn_exp2f)
    return __builtin_amdgcn_exp2f(x);
#else
    return exp2f(x);
#endif
}

// 16x16x16 bf16 MFMA (k=16): verified working (passed correctness)
__device__ __forceinline__ f32x4 mfma_16x16x16_bf16(bf16x4 a, bf16x4 b, f32x4 c) {
#if __has_builtin(__builtin_amdgcn_mfma_f32_16x16x16_bf16)
    return __builtin_amdgcn_mfma_f32_16x16x16_bf16(a, b, c, 0, 0, 0);
#elif __has_builtin(__builtin_amdgcn_mfma_f32_16x16x16bf16_1k)
    return __builtin_amdgcn_mfma_f32_16x16x16bf16_1k(a, b, c, 0, 0, 0);
#else
    asm volatile("v_mfma_f32_16x16x16_bf16 %0, %1, %2, %0"
                 : "+v"(c) : "v"(a), "v"(b));
    return c;
#endif
}

// ---------------------------------------------------------------------------
__global__ void convert_x4(const float4* __restrict__ src, ushort4* __restrict__ dst, int n4) {
    int i = blockIdx.x * blockDim.x + threadIdx.x;
    if (i >= n4) return;
    float4 v = src[i];
    ushort4 o;
    o.x = bf16bits(v.x); o.y = bf16bits(v.y);
    o.z = bf16bits(v.z); o.w = bf16bits(v.w);
    dst[i] = o;
}

__global__ void convert_biases(const float* __restrict__ b0, const float* __restrict__ b1,
                               const float* __restrict__ b2, const float* __restrict__ b3,
                               bf16* __restrict__ dst) {
    int i = blockIdx.x * blockDim.x + threadIdx.x;   // 0..4095
    int which = i >> 10, j = i & 1023;
    const float* src = (which == 0) ? b0 : (which == 1) ? b1 : (which == 2) ? b2 : b3;
    dst[i] = __float2bfloat16(src[j]);
}

// ---------------------------------------------------------------------------
// LDS-tiled transpose, fused over Wq/Wk/Wv: z = which*16 + h.
// ---------------------------------------------------------------------------
__global__ __launch_bounds__(256) void transpose_qkv_kernel(
    const float* __restrict__ Wq, const float* __restrict__ Wk, const float* __restrict__ Wv,
    bf16* __restrict__ WqT, bf16* __restrict__ WkT, bf16* __restrict__ WvT) {
    __shared__ float tile[64][65];
    const int which = blockIdx.z >> 4, h = blockIdx.z & 15;
    const float* W  = ((which == 0) ? Wq  : (which == 1) ? Wk  : Wv)  + (size_t)h * CDIM * DH;
    bf16*        WT = ((which == 0) ? WqT : (which == 1) ? WkT : WvT) + (size_t)h * CDIM * DH;
    const int c0 = blockIdx.x * 64;
    for (int it = 0; it < 16; it++) {
        int e = it * 256 + threadIdx.x;
        int r = e >> 6, col = e & 63;
        tile[r][col] = W[(size_t)(c0 + r) * DH + col];
    }
    __syncthreads();
    for (int it = 0; it < 16; it++) {
        int e = it * 256 + threadIdx.x;
        int r = e >> 6, col = e & 63;
        WT[(size_t)r * CDIM + c0 + col] = __float2bfloat16(tile[col][r]);
    }
}

__global__ __launch_bounds__(256) void transpose_wo_kernel(
    const float* __restrict__ W, bf16* __restrict__ WT) {
    __shared__ float tile[64][65];
    const int c0 = blockIdx.x * 64, d0 = blockIdx.y * 64;
    for (int it = 0; it < 16; it++) {
        int e = it * 256 + threadIdx.x;
        int r = e >> 6, col = e & 63;
        tile[r][col] = W[(size_t)(c0 + r) * CDIM + d0 + col];
    }
    __syncthreads();
    for (int it = 0; it < 16; it++) {
        int e = it * 256 + threadIdx.x;
        int r = e >> 6, col = e & 63;
        WT[(size_t)(d0 + r) * CDIM + c0 + col] = __float2bfloat16(tile[col][r]);
    }
}

// ---------------------------------------------------------------------------
// 128x128 MFMA GEMM, QKV variant (r13 single-buffer structure restored --
// r14's dbuf+single-barrier regressed ~8us: the trailing __syncthreads
// drains the just-issued prefetch anyway (r6 lesson) while doubling LDS).
//  - T1 XCD swizzle (r13, measured win): XCD = M-octant.
//  - z==2 (V) epilogue writes Vt[bh][d][t] DIRECTLY (r indexes 4 consecutive
//    t -> one ushort4 per fragment, bit-identical values) -- the separate
//    transpose_v kernel (32MB round-trip + 1 launch) is eliminated.
// Q pre-scaled by (1/32)*log2(e) so attention can use native exp2.
// ---------------------------------------------------------------------------
__global__ __launch_bounds__(256) void proj_qkv_kernel(
    const bf16* __restrict__ X,
    const bf16* __restrict__ WqT, const bf16* __restrict__ WkT, const bf16* __restrict__ WvT,
    const bf16* __restrict__ bq,  const bf16* __restrict__ bk,  const bf16* __restrict__ bvv,
    bf16* __restrict__ Qo, bf16* __restrict__ Ko, bf16* __restrict__ Vt)
{
    // XCD-aware decode (lin%8 = XCD by HW round-robin)
    const int lin  = blockIdx.x + (int)gridDim.x * (blockIdx.y + (int)gridDim.y * blockIdx.z);
    const int xcd  = lin & 7;
    const int s    = lin >> 3;          // 0..191
    const int mloc = s & 7;             // M-tile within octant
    const int rest = s >> 3;            // 0..23
    const int nblk = rest & 7;          // N-tile
    const int z    = rest >> 3;         // 0..2

    const bf16* Bt   = (z == 0) ? WqT : (z == 1) ? WkT : WvT;
    const bf16* bias = (z == 0) ? bq  : (z == 1) ? bk  : bvv;

    __shared__ __align__(16) bf16 As[128 * 32];
    __shared__ __align__(16) bf16 Bs[128 * 32];

    const int tid  = threadIdx.x;
    const int lane = tid & 63;
    const int wave = tid >> 6;
    const int wr = wave >> 1, wc = wave & 1;
    const int l15 = lane & 15, quad = lane >> 4;

    const int blockM = (xcd * 8 + mloc) * 128;
    const int blockN = nblk * 128;

    f32x4 acc[4][4];
    for (int i = 0; i < 4; i++)
        for (int j = 0; j < 4; j++)
            acc[i][j] = (f32x4){0.f, 0.f, 0.f, 0.f};

    const int srow = lane >> 2, scol = (lane & 3) * 8;
    for (int k0 = 0; k0 < CDIM; k0 += 32) {
        for (int cc = 0; cc < 2; cc++) {
            int chunk = wave * 2 + cc;
            int row = chunk * 16 + srow;
            async_ld16(&X [(size_t)(blockM + row) * CDIM + k0 + scol], &As[chunk * 512]);
            async_ld16(&Bt[(size_t)(blockN + row) * CDIM + k0 + scol], &Bs[chunk * 512]);
        }
        __syncthreads();

        bf16x8 af[4], bfr[4];
        for (int mi = 0; mi < 4; mi++)
            af[mi] = *(const bf16x8*)&As[(wr * 64 + mi * 16 + l15) * 32 + quad * 8];
        for (int ni = 0; ni < 4; ni++)
            bfr[ni] = *(const bf16x8*)&Bs[(wc * 64 + ni * 16 + l15) * 32 + quad * 8];

        for (int mi = 0; mi < 4; mi++)
            for (int ni = 0; ni < 4; ni++)
                acc[mi][ni] = __builtin_amdgcn_mfma_f32_16x16x32_bf16(
                    af[mi], bfr[ni], acc[mi][ni], 0, 0, 0);
        __syncthreads();
    }

    for (int mi = 0; mi < 4; mi++) {
        int mbase = blockM + wr * 64 + mi * 16 + quad * 4;
        int b = mbase >> 11, t = mbase & 2047;
        for (int ni = 0; ni < 4; ni++) {
            int n = blockN + wc * 64 + ni * 16 + l15;
            float bval = __bfloat162float(bias[n]);
            int h = n >> 6, d = n & 63;
            if (z == 2) {
                // V: write transposed layout directly, 4 consecutive t
                unsigned short pk[4];
                for (int r = 0; r < 4; r++) pk[r] = bf16bits(acc[mi][ni][r] + bval);
                *(ushort4*)&Vt[(((size_t)b * HDIM + h) * DH + d) * TDIM + t] = *(ushort4*)pk;
            } else {
                for (int r = 0; r < 4; r++) {
                    float val = acc[mi][ni][r] + bval;
                    size_t idx = (((size_t)b * HDIM + h) * TDIM + (t + r)) * DH + d;
                    if (z == 0) Qo[idx] = __float2bfloat16(val * 0.045084439f); // (1/32)*log2(e)
                    else        Ko[idx] = __float2bfloat16(val);
                }
            }
        }
    }
}

// ---------------------------------------------------------------------------
// Output projection: Y[M,K] @ WoT[N,K]^T + bo -> fp32 Out
// r13 single-buffer structure + T1 XCD swizzle (XCD = M-octant).
// ---------------------------------------------------------------------------
__global__ __launch_bounds__(256) void proj_out_kernel(
    const bf16* __restrict__ X, const bf16* __restrict__ Bt,
    const bf16* __restrict__ bias, float* __restrict__ Out)
{
    const int lin  = blockIdx.x + (int)gridDim.x * blockIdx.y;   // 0..511
    const int xcd  = lin & 7;
    const int s    = lin >> 3;      // 0..63
    const int mloc = s & 7;
    const int nblk = s >> 3;        // 0..7

    __shared__ __align__(16) bf16 As[128 * 32];
    __shared__ __align__(16) bf16 Bs[128 * 32];

    const int tid  = threadIdx.x;
    const int lane = tid & 63;
    const int wave = tid >> 6;
    const int wr = wave >> 1, wc = wave & 1;
    const int l15 = lane & 15, quad = lane >> 4;

    const int blockM = (xcd * 8 + mloc) * 128;
    const int blockN = nblk * 128;

    f32x4 acc[4][4];
    for (int i = 0; i < 4; i++)
        for (int j = 0; j < 4; j++)
            acc[i][j] = (f32x4){0.f, 0.f, 0.f, 0.f};

    const int srow = lane >> 2, scol = (lane & 3) * 8;
    for (int k0 = 0; k0 < CDIM; k0 += 32) {
        for (int cc = 0; cc < 2; cc++) {
            int chunk = wave * 2 + cc;
            int row = chunk * 16 + srow;
            async_ld16(&X [(size_t)(blockM + row) * CDIM + k0 + scol], &As[chunk * 512]);
            async_ld16(&Bt[(size_t)(blockN + row) * CDIM + k0 + scol], &Bs[chunk * 512]);
        }
        __syncthreads();

        bf16x8 af[4], bfr[4];
        for (int mi = 0; mi < 4; mi++)
            af[mi] = *(const bf16x8*)&As[(wr * 64 + mi * 16 + l15) * 32 + quad * 8];
        for (int ni = 0; ni < 4; ni++)
            bfr[ni] = *(const bf16x8*)&Bs[(wc * 64 + ni * 16 + l15) * 32 + quad * 8];

        for (int mi = 0; mi < 4; mi++)
            for (int ni = 0; ni < 4; ni++)
                acc[mi][ni] = __builtin_amdgcn_mfma_f32_16x16x32_bf16(
                    af[mi], bfr[ni], acc[mi][ni], 0, 0, 0);
        __syncthreads();
    }

    for (int mi = 0; mi < 4; mi++) {
        int mbase = blockM + wr * 64 + mi * 16 + quad * 4;
        for (int ni = 0; ni < 4; ni++) {
            int n = blockN + wc * 64 + ni * 16 + l15;
            float bval = __bfloat162float(bias[n]);
            for (int r = 0; r < 4; r++)
                Out[(size_t)(mbase + r) * CDIM + n] = acc[mi][ni][r] + bval;
        }
    }
}

// ---------------------------------------------------------------------------
// Flash attention, causal.  r12/r13 version unchanged (81-82us measured):
// 128-q tiles, 4 waves, 2 q-groups/wave, gload_lds swizzle staging,
// 2-buffer single-barrier loop, T1 XCD swizzle (FETCH 112->24.6MB).
// ---------------------------------------------------------------------------
__global__ __launch_bounds__(256, 4) void attn_kernel(
    const bf16* __restrict__ Q, const bf16* __restrict__ Kb,
    const bf16* __restrict__ Vt, bf16* __restrict__ Y)
{
    // XCD-aware decode: lin -> (bh, qT) such that lin%8 is constant per bh
    const int lin  = blockIdx.x + (int)gridDim.x * blockIdx.y;   // 0..1023
    const int slot = lin >> 3;                                   // 0..127
    const int bh   = (lin & 7) * 8 + (slot >> 4);                // 0..63
    const int qT   = 15 - (slot & 15);                           // heavy first
    const int qBase = qT * 128;
    const int tid  = threadIdx.x;
    const int lane = tid & 63, wave = tid >> 6;          // wave 0..3
    const int l15 = lane & 15, quad = lane >> 4;

    __shared__ __align__(16) bf16 smem[2 * 2 * 64 * 64];     // 32 KiB, 2 bufs
    // buf b: K at smem + b*8192, V at smem + b*8192 + 4096 (stride-64 rows)

    // Q B-fragments: group g rows = qBase + g*64 + wave*16 + l15
    bf16x8 qf[2][2];
    for (int g = 0; g < 2; g++) {
        const size_t qrow = (size_t)bh * TDIM + qBase + g * 64 + wave * 16 + l15;
        qf[g][0] = *(const bf16x8*)&Q[qrow * DH + quad * 8];
        qf[g][1] = *(const bf16x8*)&Q[qrow * DH + 32 + quad * 8];
    }

    // O^T accumulators: o[g][mt][r] -> d = mt*16+quad*4+r, q = l15
    f32x4 o[2][4];
    for (int g = 0; g < 2; g++)
        for (int mt = 0; mt < 4; mt++)
            o[g][mt] = (f32x4){0.f, 0.f, 0.f, 0.f};
    float lsum[2] = {0.f, 0.f};

    // --- staging geometry: wave w covers rows w*16 .. w*16+15 --------------
    // lane l: row = base + (l>>3); base%8==0 so row&7 == l>>3.
    // inverse-swizzled source col8 = (l&7) ^ (l>>3)  (per-lane constant)
    const int srow = (wave << 4) + (lane >> 3);
    const int ssc  = (((lane & 7) ^ (lane >> 3)) << 3);         // elem offset
    const bf16* kSrc0 = Kb + ((size_t)bh * TDIM + srow) * DH + ssc;   // +kt*64*DH, +8*DH
    const bf16* vSrc0 = Vt + ((size_t)bh * DH + srow) * TDIM + ssc;   // +kt*64,    +8*TDIM

    // read-side swizzle constants
    const int swA   = l15 & 7;                         // row&7 for fragment rows
    const int kcol0 = ((quad ^ swA) << 3);             // logical col8=quad
    const int kcol1 = (((4 + quad) ^ swA) << 3);       // logical col8=4+quad
    const int u2    = quad >> 1, intra = ((quad & 1) << 2);

    const int nkt  = 2 * qT + 2;
    const int qloc = wave * 16 + l15;    // q offset within a group's 64 rows

    // wave-private staging bases (buffer-relative)
    bf16* kD0 = smem + (wave * 16) * 64;
    bf16* vD0 = smem + 4096 + (wave * 16) * 64;

#define STAGE(tile, buf)                                            \
    do {                                                            \
        const bf16* kS_ = kSrc0 + (size_t)(tile) * 64 * DH;         \
        const bf16* vS_ = vSrc0 + (size_t)(tile) * 64;              \
        bf16* kD_ = kD0 + (buf) * 8192;                             \
        bf16* vD_ = vD0 + (buf) * 8192;                             \
        async_ld16(kS_,            kD_);                            \
        async_ld16(kS_ + 8 * DH,   kD_ + 8 * 64);                   \
        async_ld16(vS_,            vD_);                            \
        async_ld16(vS_ + 8 * TDIM, vD_ + 8 * 64);                   \
    } while (0)

    STAGE(0, 0);
    __syncthreads();   // tile 0 resident

    int cur = 0;
    for (int kt = 0; kt < nkt; kt++) {
        if (kt + 1 < nkt) STAGE(kt + 1, cur ^ 1);   // issued early, drained by
                                                    // the trailing barrier
        const bf16* Ks = smem + cur * 8192;
        const bf16* Vs = Ks + 4096;

        const int dg = kt - 2 * qT;   // <0: both full; 0: g0 diag; 1: g1 diag, g0 done
        for (int nt = 0; nt < 4; nt++) {
            // K A-frags for this 16-key chunk (swizzled cols, shared by groups)
            bf16x8 kf0 = *(const bf16x8*)&Ks[(nt * 16 + l15) * 64 + kcol0];
            bf16x8 kf1 = *(const bf16x8*)&Ks[(nt * 16 + l15) * 64 + kcol1];
            // V A-frags (16x16x16): logical elem col nt*16+quad*4
            bf16x4 vA[4];
            for (int mt = 0; mt < 4; mt++)
                vA[mt] = *(const bf16x4*)&Vs[(mt * 16 + l15) * 64 +
                                             (((nt * 2 + u2) ^ swA) << 3) + intra];

            for (int g = 0; g < 2; g++) {
                if (dg == 1 && g == 0) continue;      // group 0 causal range done
                f32x4 s = (f32x4){0.f, 0.f, 0.f, 0.f};
                s = __builtin_amdgcn_mfma_f32_16x16x32_bf16(kf0, qf[g][0], s, 0, 0, 0);
                s = __builtin_amdgcn_mfma_f32_16x16x32_bf16(kf1, qf[g][1], s, 0, 0, 0);

                const bool diag = (dg == g);
                bf16x4 pb;
                for (int r = 0; r < 4; r++) {
                    float pe = fast_exp2(s[r]);
                    if (diag && (nt * 16 + quad * 4 + r > qloc)) pe = 0.f;
                    lsum[g] += pe;
                    pb[r] = (short)bf16bits(pe);
                }
                for (int mt = 0; mt < 4; mt++)
                    o[g][mt] = mfma_16x16x16_bf16(vA[mt], pb, o[g][mt]);
            }
        }
        __syncthreads();   // drains kt+1 loads + protects buffer swap
        cur ^= 1;
    }
#undef STAGE

    // ---- epilogue: per group, normalize, LDS transpose, coalesced store ----
    const int b = bh >> 4, h = bh & 15;
    unsigned short* sm = (unsigned short*)smem;
    for (int g = 0; g < 2; g++) {
        float v = lsum[g];
        v += __shfl_xor(v, 16, 64);
        v += __shfl_xor(v, 32, 64);
        const float inv = 1.0f / v;

        // o -> LDS wave-private slice [q row][d col], stride 72
        for (int mt = 0; mt < 4; mt++) {
            unsigned short pk[4];
            for (int r = 0; r < 4; r++) pk[r] = bf16bits(o[g][mt][r] * inv);
            *(ushort4*)&sm[(wave * 16 + l15) * 72 + mt * 16 + quad * 4] = *(ushort4*)pk;
        }
        // same-wave readback, coalesced global store
        const int qq = lane >> 2, part = lane & 3;
        const int t = qBase + g * 64 + wave * 16 + qq;
        uint4 c0 = *(const uint4*)&sm[(wave * 16 + qq) * 72 + part * 16];
        uint4 c1 = *(const uint4*)&sm[(wave * 16 + qq) * 72 + part * 16 + 8];
        *(uint4*)&Y[((size_t)b * TDIM + t) * CDIM + h * DH + part * 16]     = c0;
        *(uint4*)&Y[((size_t)b * TDIM + t) * CDIM + h * DH + part * 16 + 8] = c1;
    }
}

// ---------------------------------------------------------------------------
extern "C" void kernel_launch(void* const* d_in, const int* in_sizes, int n_in,
                              void* d_out, int out_size, void* d_ws, size_t ws_size,
                              hipStream_t stream) {
    (void)in_sizes; (void)n_in; (void)out_size; (void)ws_size;

    char* ws = (char*)d_ws;
    const size_t SZ_BHTD = (size_t)BDIM * HDIM * TDIM * DH * sizeof(bf16);  // 16 MiB
    const size_t SZ_W    = (size_t)HDIM * CDIM * DH * sizeof(bf16);         // 2 MiB
    bf16* Qb  = (bf16*)(ws);
    bf16* Kb  = (bf16*)(ws + SZ_BHTD);
    bf16* Vt  = (bf16*)(ws + 2 * SZ_BHTD);
    bf16* Y   = (bf16*)(ws + 3 * SZ_BHTD);
    bf16* WqT = (bf16*)(ws + 4 * SZ_BHTD);
    bf16* WkT = (bf16*)(ws + 4 * SZ_BHTD + SZ_W);
    bf16* WvT = (bf16*)(ws + 4 * SZ_BHTD + 2 * SZ_W);
    bf16* WoT = (bf16*)(ws + 4 * SZ_BHTD + 3 * SZ_W);
    bf16* xC  = (bf16*)(ws + 4 * SZ_BHTD + 4 * SZ_W);                       // 16 MiB
    bf16* bqC = (bf16*)(ws + 5 * SZ_BHTD + 4 * SZ_W);
    bf16* bkC = bqC + 1024;
    bf16* bvC = bqC + 2048;
    bf16* boC = bqC + 3072;

    const int nX4 = (BDIM * TDIM * CDIM) / 4;
    convert_x4<<<nX4 / 256, 256, 0, stream>>>((const float4*)d_in[0], (ushort4*)xC, nX4);
    convert_biases<<<16, 256, 0, stream>>>((const float*)d_in[2], (const float*)d_in[4],
                                           (const float*)d_in[6], (const float*)d_in[8], bqC);

    transpose_qkv_kernel<<<dim3(CDIM / 64, 1, 48), 256, 0, stream>>>(
        (const float*)d_in[1], (const float*)d_in[3], (const float*)d_in[5], WqT, WkT, WvT);
    transpose_wo_kernel<<<dim3(CDIM / 64, CDIM / 64), 256, 0, stream>>>(
        (const float*)d_in[7], WoT);

    dim3 gq(CDIM / 128, (BDIM * TDIM) / 128, 3);
    proj_qkv_kernel<<<gq, 256, 0, stream>>>(xC, WqT, WkT, WvT, bqC, bkC, bvC, Qb, Kb, Vt);

    attn_kernel<<<dim3(TDIM / 128, BDIM * HDIM), 256, 0, stream>>>(Qb, Kb, Vt, Y);

    proj_out_kernel<<<dim3(CDIM / 128, (BDIM * TDIM) / 128), 256, 0, stream>>>(
        Y, WoT, boC, (float*)d_out);
}